// Round 11
// baseline (67.123 us; speedup 1.0000x reference)
//
#include <hip/hip_runtime.h>
#include <stdint.h>

// Problem constants
#define BB 1024
#define MM 128
#define KK 32
#define NEDGE (BB * MM * KK)   // 4194304
#define BPB 4                  // blocks per batch
#define ROWS_PER_WAVE (MM / (4 * BPB))  // 8
#define HALF (ROWS_PER_WAVE / 2)        // 4

typedef unsigned int uint2v __attribute__((ext_vector_type(2)));

#define DPPS1 "quad_perm:[1,0,3,2] row_mask:0xf bank_mask:0xf"   // xor 1
#define DPPS2 "quad_perm:[2,3,0,1] row_mask:0xf bank_mask:0xf"   // xor 2

// swizzle compare-exchange: partner on LDS pipe, min/max/cndmask on VALU.
#define CEXS(K, ST, MSK)                                                      \
  { unsigned p_ = (unsigned)__builtin_amdgcn_ds_swizzle((int)(K), ((ST) << 10) | 0x1F); \
    unsigned mn_ = __builtin_elementwise_min((K), p_);                        \
    unsigned mx_ = __builtin_elementwise_max((K), p_);                        \
    asm("v_cndmask_b32 %0, %1, %2, %3" : "=v"(K) : "v"(mx_), "v"(mn_), "s"(MSK)); }

// 4-key fused DPP compare-exchange (strides 1,2)
#define CEXD4(DPPSTR, M)                                                      \
  { unsigned tA0, tA1, tB0, tB1;                                              \
    asm("v_min_u32_dpp %4, %0, %0 " DPPSTR "\n\t"                             \
        "v_max_u32_dpp %5, %0, %0 " DPPSTR "\n\t"                             \
        "v_min_u32_dpp %6, %1, %1 " DPPSTR "\n\t"                             \
        "v_max_u32_dpp %7, %1, %1 " DPPSTR "\n\t"                             \
        "v_cndmask_b32 %0, %5, %4, %8\n\t"                                    \
        "v_cndmask_b32 %1, %7, %6, %8\n\t"                                    \
        "v_min_u32_dpp %4, %2, %2 " DPPSTR "\n\t"                             \
        "v_max_u32_dpp %5, %2, %2 " DPPSTR "\n\t"                             \
        "v_min_u32_dpp %6, %3, %3 " DPPSTR "\n\t"                             \
        "v_max_u32_dpp %7, %3, %3 " DPPSTR "\n\t"                             \
        "v_cndmask_b32 %2, %5, %4, %8\n\t"                                    \
        "v_cndmask_b32 %3, %7, %6, %8"                                        \
        : "+v"(K0a), "+v"(K1a), "+v"(K0b), "+v"(K1b),                         \
          "=&v"(tA0), "=&v"(tA1), "=&v"(tB0), "=&v"(tB1)                      \
        : "s"(M)); }

// 2-key fused DPP compare-exchange (cleans)
#define CEXD2(KA, KB, DPPSTR, M)                                              \
  { unsigned t0_, t1_, t2_, t3_;                                              \
    asm("s_nop 0\n\t"                                                         \
        "v_min_u32_dpp %2, %0, %0 " DPPSTR "\n\t"                             \
        "v_max_u32_dpp %3, %0, %0 " DPPSTR "\n\t"                             \
        "v_min_u32_dpp %4, %1, %1 " DPPSTR "\n\t"                             \
        "v_max_u32_dpp %5, %1, %1 " DPPSTR "\n\t"                             \
        "v_cndmask_b32 %0, %3, %2, %6\n\t"                                    \
        "v_cndmask_b32 %1, %5, %4, %6"                                        \
        : "+v"(KA), "+v"(KB), "=&v"(t0_), "=&v"(t1_), "=&v"(t2_), "=&v"(t3_)  \
        : "s"(M)); }

#define SW4(ST, MSK) CEXS(K0a, ST, MSK) CEXS(K1a, ST, MSK) CEXS(K0b, ST, MSK) CEXS(K1b, ST, MSK)
#define XOR4(V) K0a ^= (V); K1a ^= (V); K0b ^= (V); K1b ^= (V);

// the full phase-1 network (sorts the four 32-blocks, direction-folded);
// entry state: keys folded with f2 / nf2; exit state: f32c / nf32.
#define PHASE1_NET                                                            \
        CEXD4(DPPS1, m1)                                                      \
        XOR4(t24)                                                             \
        CEXD4(DPPS2, m2) CEXD4(DPPS1, m1)                                     \
        XOR4(t48)                                                             \
        SW4(4, m4) CEXD4(DPPS2, m2) CEXD4(DPPS1, m1)                          \
        XOR4(t816)                                                            \
        SW4(8, m8) SW4(4, m4) CEXD4(DPPS2, m2) CEXD4(DPPS1, m1)               \
        XOR4(t1632)                                                           \
        SW4(16, m16) SW4(8, m8) SW4(4, m4) CEXD4(DPPS2, m2) CEXD4(DPPS1, m1)

// min over {v[l], v[l^32]} — bitonic split across the 32-lane halves
static __device__ __forceinline__ unsigned minxor32(unsigned k) {
#if __has_builtin(__builtin_amdgcn_permlane32_swap)
    uint2v s = __builtin_amdgcn_permlane32_swap(k, k, false, false);
    return __builtin_elementwise_min(s.x, s.y);
#else
    unsigned p = (unsigned)__shfl_xor((int)k, 32, 64);
    return __builtin_elementwise_min(k, p);
#endif
}

// DIAGNOSTIC BUILD (round 11): phase-1 network applied TWICE per row.
// A sorting network's output is the unique sorted order, so the second
// application (after unfolding back to entry state) is a bitwise identity —
// output is unchanged; only the sort's cost is doubled. This splits dur_us
// into sort vs scaffolding empirically.
__global__ __launch_bounds__(256, 4) void knn_edges_kernel(const float* __restrict__ pos,
                                                           float* __restrict__ out) {
    __shared__ float px[MM], py[MM], pz[MM], sqs[MM];
    const int blk = blockIdx.x;
    const int b = blk >> 2;            // blk / BPB
    const int sub = blk & (BPB - 1);
    const int tid = threadIdx.x;

    if (tid < MM) {
        const float* p = pos + (size_t)(b * MM + tid) * 3;
        float x = p[0], y = p[1], z = p[2];
        px[tid] = x; py[tid] = y; pz[tid] = z;
        sqs[tid] = __fadd_rn(__fadd_rn(__fmul_rn(x, x), __fmul_rn(y, y)), __fmul_rn(z, z));
    }
    __syncthreads();

    const int wave = tid >> 6;
    const int lane = tid & 63;
    const int g = lane & 31;
    const bool hi = lane >= 32;
    const unsigned upper = hi ? ~0u : 0u;

    // ---- the 5 comparator masks, anchored once into SGPR pairs ----
    unsigned long long m1  = 0x5555555555555555ull;
    unsigned long long m2  = 0x3333333333333333ull;
    unsigned long long m4  = 0x0F0F0F0F0F0F0F0Full;
    unsigned long long m8  = 0x00FF00FF00FF00FFull;
    unsigned long long m16 = 0x0000FFFF0000FFFFull;
    asm("" : "+s"(m1), "+s"(m2), "+s"(m4), "+s"(m8), "+s"(m16));

    // ---- per-lane direction-fold constants ----
    auto dmask = [&](int s) -> unsigned {
        unsigned zer = ((g & s) == 0) ? ~0u : 0u;
        return ~(zer ^ upper);   // XNOR: equal -> ~0 (complement), else 0
    };
    const unsigned f2    = dmask(2);
    const unsigned nf2   = ~f2;
    const unsigned f4c   = dmask(4);
    const unsigned f8c   = dmask(8);
    const unsigned f16c  = dmask(16);
    const unsigned f32c  = dmask(32);
    const unsigned t24   = f2 ^ f4c;
    const unsigned t48   = f4c ^ f8c;
    const unsigned t816  = f8c ^ f16c;
    const unsigned t1632 = f16c ^ f32c;
    const unsigned nf32  = ~f32c;
    const unsigned refold = f32c ^ f2;   // exit-state -> entry-state unfold

    // per-lane candidate coordinates, hoisted across the row loop
    const int j0 = lane, j1 = lane + 64;
    const float xa = px[j0], ya = py[j0], za = pz[j0], qa = sqs[j0];
    const float xb = px[j1], yb = py[j1], zb = pz[j1], qb = sqs[j1];

    const int row0 = sub * (MM / BPB) + wave * ROWS_PER_WAVE;
    const float fbase = (float)(b * MM);   // exact in fp32

    // output streams (3 stores/lane/row)
    float* const vecbase = out + 3 * (size_t)NEDGE;
    const long e0 = (long)(b * MM + row0) * KK + g;
    float* pA = hi ? out + (size_t)NEDGE + e0 : out + e0;
    float* pB = vecbase + e0 * 3 + (hi ? 2 : 0);
    float* pC = hi ? out + 2 * (size_t)NEDGE + e0 : vecbase + e0 * 3 + 1;
    const int sC = hi ? KK : 3 * KK;
    const int oC = sC * HALF;

    for (int ii = 0; ii < HALF; ++ii) {
        const int ia = row0 + ii;
        const int ib = ia + HALF;

        const float xia = px[ia], yia = py[ia], zia = pz[ia], qia = sqs[ia];
        const float xib = px[ib], yib = py[ib], zib = pz[ib], qib = sqs[ib];

        float dot;
        dot = fmaf(xia, xa, fmaf(yia, ya, zia * za));
        unsigned K0a = ((__float_as_uint(fmaxf(fmaf(-2.0f, dot, qia + qa), 0.0f)) & 0xFFFFFF80u) | (unsigned)j0) ^ f2;
        dot = fmaf(xia, xb, fmaf(yia, yb, zia * zb));
        unsigned K1a = ((__float_as_uint(fmaxf(fmaf(-2.0f, dot, qia + qb), 0.0f)) & 0xFFFFFF80u) | (unsigned)j1) ^ nf2;
        dot = fmaf(xib, xa, fmaf(yib, ya, zib * za));
        unsigned K0b = ((__float_as_uint(fmaxf(fmaf(-2.0f, dot, qib + qa), 0.0f)) & 0xFFFFFF80u) | (unsigned)j0) ^ f2;
        dot = fmaf(xib, xb, fmaf(yib, yb, zib * zb));
        unsigned K1b = ((__float_as_uint(fmaxf(fmaf(-2.0f, dot, qib + qb), 0.0f)) & 0xFFFFFF80u) | (unsigned)j1) ^ nf2;

        // ---- phase 1 (real) ----
        PHASE1_NET

        // ---- phase 1 AGAIN (bitwise identity; diagnostic cost-doubling) ----
        XOR4(refold)
        PHASE1_NET

        // ---- exit complements + shuffle-free bitonic split ----
        unsigned Ca = (__builtin_elementwise_min(K0a ^ f32c, K1a ^ nf32)) ^ upper;
        unsigned Cb = (__builtin_elementwise_min(K0b ^ f32c, K1b ^ nf32)) ^ upper;

        // ---- dual clean (lower asc / upper desc, folded) ----
        CEXS(Ca, 16, m16) CEXS(Cb, 16, m16)
        CEXS(Ca, 8,  m8)  CEXS(Cb, 8,  m8)
        CEXS(Ca, 4,  m4)  CEXS(Cb, 4,  m4)
        CEXD2(Ca, Cb, DPPS2, m2)
        CEXD2(Ca, Cb, DPPS1, m1)

        // ---- split across halves, final ascending clean ----
        unsigned Ma = minxor32(Ca ^ upper);
        unsigned Mb = minxor32(Cb ^ upper);
        CEXS(Ma, 16, m16) CEXS(Mb, 16, m16)
        CEXS(Ma, 8,  m8)  CEXS(Mb, 8,  m8)
        CEXS(Ma, 4,  m4)  CEXS(Mb, 4,  m4)
        CEXD2(Ma, Mb, DPPS2, m2)
        CEXD2(Ma, Mb, DPPS1, m1)

        // ---- epilogue row a ----
        {
            const bool taken = Ma < 0x41C80000u;   // d2 < 25.0
            const int j = (int)(Ma & 127u);
            const int sel = taken ? j : ia;
            float dxv = __fsub_rn(px[sel], xia);
            float dyv = __fsub_rn(py[sel], yia);
            float dzv = __fsub_rn(pz[sel], zia);
            float w = sqrtf(fmaf(dzv, dzv, fmaf(dyv, dyv, dxv * dxv)));
            const float fsrc = fbase + (float)sel;
            const float fnode = fbase + (float)ia;
            pA[0] = hi ? fnode : fsrc;
            pB[0] = hi ? dzv : dxv;
            pC[0] = hi ? w : dyv;
        }
        // ---- epilogue row b ----
        {
            const bool taken = Mb < 0x41C80000u;
            const int j = (int)(Mb & 127u);
            const int sel = taken ? j : ib;
            float dxv = __fsub_rn(px[sel], xib);
            float dyv = __fsub_rn(py[sel], yib);
            float dzv = __fsub_rn(pz[sel], zib);
            float w = sqrtf(fmaf(dzv, dzv, fmaf(dyv, dyv, dxv * dxv)));
            const float fsrc = fbase + (float)sel;
            const float fnode = fbase + (float)ib;
            pA[HALF * KK] = hi ? fnode : fsrc;
            pB[HALF * 3 * KK] = hi ? dzv : dxv;
            pC[oC] = hi ? w : dyv;
        }
        pA += KK; pB += 3 * KK; pC += sC;
    }
}

extern "C" void kernel_launch(void* const* d_in, const int* in_sizes, int n_in,
                              void* d_out, int out_size, void* d_ws, size_t ws_size,
                              hipStream_t stream) {
    const float* pos = (const float*)d_in[0];
    float* out = (float*)d_out;
    hipLaunchKernelGGL(knn_edges_kernel, dim3(BB * BPB), dim3(256), 0, stream, pos, out);
}

// Round 12
// 39.684 us; speedup vs baseline: 1.6914x; 1.6914x over previous
//
#include <hip/hip_runtime.h>
#include <stdint.h>

// Problem constants
#define BB 1024
#define MM 128
#define KK 32
#define NEDGE (BB * MM * KK)   // 4194304
#define BPB 4                  // blocks per batch
#define ROWS_PER_WAVE (MM / (4 * BPB))  // 8

#define TH 0x41C80000u         // f32 bits of 25.0 (low 7 bits zero)
#define INFK 0x7F800000u

typedef unsigned int uint2v __attribute__((ext_vector_type(2)));

#define DPP1 "quad_perm:[1,0,3,2] row_mask:0xf bank_mask:0xf"   // xor 1
#define DPP2 "quad_perm:[2,3,0,1] row_mask:0xf bank_mask:0xf"   // xor 2

// ---- comparator primitives: keep-min where mask bit set ----
template<int ST>
static __device__ __forceinline__ void cexd(unsigned& k, unsigned long long msk) {
    unsigned t0, t1;
    if constexpr (ST == 1) {
        asm("s_nop 1\n\t"
            "v_min_u32_dpp %1, %0, %0 " DPP1 "\n\t"
            "v_max_u32_dpp %2, %0, %0 " DPP1 "\n\t"
            "v_cndmask_b32 %0, %2, %1, %3"
            : "+v"(k), "=&v"(t0), "=&v"(t1) : "s"(msk));
    } else {
        asm("s_nop 1\n\t"
            "v_min_u32_dpp %1, %0, %0 " DPP2 "\n\t"
            "v_max_u32_dpp %2, %0, %0 " DPP2 "\n\t"
            "v_cndmask_b32 %0, %2, %1, %3"
            : "+v"(k), "=&v"(t0), "=&v"(t1) : "s"(msk));
    }
}

template<int ST>
static __device__ __forceinline__ void cexs(unsigned& k, unsigned long long msk) {
    unsigned p = (unsigned)__builtin_amdgcn_ds_swizzle((int)k, (ST << 10) | 0x1F);
    unsigned mn = __builtin_elementwise_min(k, p);
    unsigned mx = __builtin_elementwise_max(k, p);
    asm("v_cndmask_b32 %0, %1, %2, %3" : "=v"(k) : "v"(mx), "v"(mn), "s"(msk));
}

// stride-32 compare-exchange across the 32-lane halves
static __device__ __forceinline__ void cex32f(unsigned& k, unsigned long long msk) {
#if __has_builtin(__builtin_amdgcn_permlane32_swap)
    uint2v s = __builtin_amdgcn_permlane32_swap(k, k, false, false);
    unsigned mn = __builtin_elementwise_min(s.x, s.y);
    unsigned mx = __builtin_elementwise_max(s.x, s.y);
#else
    unsigned p = (unsigned)__shfl_xor((int)k, 32, 64);
    unsigned mn = __builtin_elementwise_min(k, p);
    unsigned mx = __builtin_elementwise_max(k, p);
#endif
    asm("v_cndmask_b32 %0, %1, %2, %3" : "=v"(k) : "v"(mx), "v"(mn), "s"(msk));
}

// min over {v[l], v[l^32]}
static __device__ __forceinline__ unsigned minxor32(unsigned k) {
#if __has_builtin(__builtin_amdgcn_permlane32_swap)
    uint2v s = __builtin_amdgcn_permlane32_swap(k, k, false, false);
    return __builtin_elementwise_min(s.x, s.y);
#else
    unsigned p = (unsigned)__shfl_xor((int)k, 32, 64);
    return __builtin_elementwise_min(k, p);
#endif
}

static __device__ __forceinline__ unsigned mbcnt64(unsigned long long m) {
    unsigned t = __builtin_amdgcn_mbcnt_lo((unsigned)m, 0u);
    return __builtin_amdgcn_mbcnt_hi((unsigned)(m >> 32), t);
}

// grid = BB*BPB blocks of 256 threads; each wave handles 8 rows.
// Per row: 128 candidates (2/lane), key = (f32bits(max(d2,0)) & ~0x7F) | j.
// Fast path (survivors<=64, ~91% of rows): LDS-compact survivors to 1 key/lane,
// bitonic sort-64 (21 stages). Slow path: round-9 two-key network (40 stages).
__global__ __launch_bounds__(256, 4) void knn_edges_kernel(const float* __restrict__ pos,
                                                           float* __restrict__ out) {
    __shared__ float px[MM], py[MM], pz[MM], sqs[MM];
    __shared__ unsigned comp[4][64];
    const int blk = blockIdx.x;
    const int b = blk >> 2;            // blk / BPB
    const int sub = blk & (BPB - 1);
    const int tid = threadIdx.x;

    if (tid < MM) {
        const float* p = pos + (size_t)(b * MM + tid) * 3;
        float x = p[0], y = p[1], z = p[2];
        px[tid] = x; py[tid] = y; pz[tid] = z;
        sqs[tid] = __fadd_rn(__fadd_rn(__fmul_rn(x, x), __fmul_rn(y, y)), __fmul_rn(z, z));
    }
    __syncthreads();

    const int wave = tid >> 6;
    const int lane = tid & 63;
    const int g = lane & 31;
    const bool hi = lane >= 32;
    const unsigned upper = hi ? ~0u : 0u;

    // ---- the 6 comparator masks, anchored once into SGPR pairs ----
    unsigned long long m1  = 0x5555555555555555ull;
    unsigned long long m2  = 0x3333333333333333ull;
    unsigned long long m4  = 0x0F0F0F0F0F0F0F0Full;
    unsigned long long m8  = 0x00FF00FF00FF00FFull;
    unsigned long long m16 = 0x0000FFFF0000FFFFull;
    unsigned long long m32 = 0x00000000FFFFFFFFull;
    asm("" : "+s"(m1), "+s"(m2), "+s"(m4), "+s"(m8), "+s"(m16), "+s"(m32));

    // ---- slow-path direction-fold constants (g-based, verified round 9) ----
    auto dmask = [&](int s) -> unsigned {
        unsigned zer = ((g & s) == 0) ? ~0u : 0u;
        return ~(zer ^ upper);   // XNOR
    };
    const unsigned f2    = dmask(2);
    const unsigned nf2   = ~f2;
    const unsigned f4c   = dmask(4);
    const unsigned f8c   = dmask(8);
    const unsigned f16c  = dmask(16);
    const unsigned f32c  = dmask(32);
    const unsigned t24   = f2 ^ f4c;
    const unsigned t48   = f4c ^ f8c;
    const unsigned t816  = f8c ^ f16c;
    const unsigned t1632 = f16c ^ f32c;
    const unsigned nf32  = ~f32c;

    // ---- fast-path fold constants (full-lane based, for the 64-sort) ----
    auto ff = [&](int s) -> unsigned { return (lane & s) ? ~0u : 0u; };
    const unsigned u2    = ff(2);
    const unsigned s24   = u2 ^ ff(4);
    const unsigned s48   = ff(4) ^ ff(8);
    const unsigned s816  = ff(8) ^ ff(16);
    const unsigned s1632 = ff(16) ^ ff(32);
    const unsigned u32   = ff(32);

    // per-lane candidate coordinates, hoisted across the row loop
    const int j0 = lane, j1 = lane + 64;
    const float xa = px[j0], ya = py[j0], za = pz[j0], qa = sqs[j0];
    const float xb = px[j1], yb = py[j1], zb = pz[j1], qb = sqs[j1];

    const int row0 = sub * (MM / BPB) + wave * ROWS_PER_WAVE;
    const float fbase = (float)(b * MM);   // exact in fp32

    // output streams (3 stores/lane/row)
    float* const vecbase = out + 3 * (size_t)NEDGE;
    const long e0 = (long)(b * MM + row0) * KK + g;
    float* pA = hi ? out + (size_t)NEDGE + e0 : out + e0;
    float* pB = vecbase + e0 * 3 + (hi ? 2 : 0);
    float* pC = hi ? out + 2 * (size_t)NEDGE + e0 : vecbase + e0 * 3 + 1;
    const int sC = hi ? KK : 3 * KK;

    float fnode = (float)(b * MM + row0);

    for (int i = row0; i < row0 + ROWS_PER_WAVE; ++i) {
        const float xi = px[i], yi = py[i], zi = pz[i], qi = sqs[i];

        // ---- raw candidate keys ----
        float dot0 = fmaf(xi, xa, fmaf(yi, ya, zi * za));
        float d20 = fmaxf(fmaf(-2.0f, dot0, qi + qa), 0.0f);
        unsigned k0r = (__float_as_uint(d20) & 0xFFFFFF80u) | (unsigned)j0;
        float dot1 = fmaf(xi, xb, fmaf(yi, yb, zi * zb));
        float d21 = fmaxf(fmaf(-2.0f, dot1, qi + qb), 0.0f);
        unsigned k1r = (__float_as_uint(d21) & 0xFFFFFF80u) | (unsigned)j1;

        // ---- survivor census (wave-uniform) ----
        unsigned long long mask0 = __ballot(k0r < TH);
        unsigned long long mask1 = __ballot(k1r < TH);
        unsigned c0 = (unsigned)__popcll(mask0);
        unsigned nsurv = c0 + (unsigned)__popcll(mask1);

        unsigned mdup;
        if (nsurv <= 64u) {
            // ===== FAST PATH: compact survivors, sort-64 =====
            unsigned dest0 = mbcnt64(mask0);
            unsigned dest1 = c0 + mbcnt64(mask1);
            if (k0r < TH) comp[wave][dest0] = k0r;
            if (k1r < TH) comp[wave][dest1] = k1r;
            asm volatile("s_waitcnt lgkmcnt(0)" ::: "memory");
            unsigned k = comp[wave][lane];
            k = ((unsigned)lane < nsurv) ? k : INFK;

            // bitonic sort-64 ascending, direction-folded (21 stages)
            k ^= u2;
            cexd<1>(k, m1);                                        // size 2
            k ^= s24;
            cexd<2>(k, m2); cexd<1>(k, m1);                        // size 4
            k ^= s48;
            cexs<4>(k, m4); cexd<2>(k, m2); cexd<1>(k, m1);        // size 8
            k ^= s816;
            cexs<8>(k, m8); cexs<4>(k, m4); cexd<2>(k, m2); cexd<1>(k, m1);   // 16
            k ^= s1632;
            cexs<16>(k, m16); cexs<8>(k, m8); cexs<4>(k, m4);
            cexd<2>(k, m2); cexd<1>(k, m1);                        // size 32
            k ^= u32;
            cex32f(k, m32); cexs<16>(k, m16); cexs<8>(k, m8); cexs<4>(k, m4);
            cexd<2>(k, m2); cexd<1>(k, m1);                        // size 64

            // lanes 0..31 hold ranks 0..31; duplicate to hi half
#if __has_builtin(__builtin_amdgcn_permlane32_swap)
            uint2v s = __builtin_amdgcn_permlane32_swap(k, k, false, false);
            unsigned partner = s.x ^ s.y ^ k;
#else
            unsigned partner = (unsigned)__shfl_xor((int)k, 32, 64);
#endif
            asm("v_cndmask_b32 %0, %1, %2, %3" : "=v"(mdup) : "v"(partner), "v"(k), "s"(m32));
        } else {
            // ===== SLOW PATH: round-9 two-key network =====
            unsigned K0 = k0r ^ f2;
            unsigned K1 = k1r ^ nf2;
#define SS2(ST, MSK) cexs<ST>(K0, MSK); cexs<ST>(K1, MSK);
            SS2(1, m1)
            K0 ^= t24; K1 ^= t24;
            SS2(2, m2) SS2(1, m1)
            K0 ^= t48; K1 ^= t48;
            SS2(4, m4) SS2(2, m2) SS2(1, m1)
            K0 ^= t816; K1 ^= t816;
            SS2(8, m8) SS2(4, m4) SS2(2, m2) SS2(1, m1)
            K0 ^= t1632; K1 ^= t1632;
            SS2(16, m16) SS2(8, m8) SS2(4, m4) SS2(2, m2) SS2(1, m1)
#undef SS2
            unsigned Ca = (__builtin_elementwise_min(K0 ^ f32c, K1 ^ nf32)) ^ upper;
            cexs<16>(Ca, m16); cexs<8>(Ca, m8); cexs<4>(Ca, m4);
            cexs<2>(Ca, m2);  cexs<1>(Ca, m1);
            unsigned Ma = minxor32(Ca ^ upper);
            cexs<16>(Ma, m16); cexs<8>(Ma, m8); cexs<4>(Ma, m4);
            cexs<2>(Ma, m2);  cexs<1>(Ma, m1);
            mdup = Ma;
        }

        // ---- epilogue: rank = lane&31 in both halves; 3 stores/lane ----
        const bool taken = mdup < TH;
        const int j = (int)(mdup & 127u);
        const int sel = taken ? j : i;

        float dxv = __fsub_rn(px[sel], xi);
        float dyv = __fsub_rn(py[sel], yi);
        float dzv = __fsub_rn(pz[sel], zi);
        float w = sqrtf(fmaf(dzv, dzv, fmaf(dyv, dyv, dxv * dxv)));
        const float fsrc = fbase + (float)sel;

        pA[0] = hi ? fnode : fsrc;
        pB[0] = hi ? dzv : dxv;
        pC[0] = hi ? w : dyv;
        pA += KK; pB += 3 * KK; pC += sC;
        fnode += 1.0f;
    }
}

extern "C" void kernel_launch(void* const* d_in, const int* in_sizes, int n_in,
                              void* d_out, int out_size, void* d_ws, size_t ws_size,
                              hipStream_t stream) {
    const float* pos = (const float*)d_in[0];
    float* out = (float*)d_out;
    hipLaunchKernelGGL(knn_edges_kernel, dim3(BB * BPB), dim3(256), 0, stream, pos, out);
}